// Round 3
// baseline (1267.414 us; speedup 1.0000x reference)
//
#include <hip/hip_runtime.h>
#include <stdint.h>

typedef unsigned short ushort_t;
typedef __attribute__((ext_vector_type(8))) __bf16 bf16x8;
typedef __attribute__((ext_vector_type(4))) float f32x4;

#define M_TOTAL   51200
#define K1        2104
#define K1P       2112     // K padded to mult of 64 (33 tiles of 64)
#define N1P       2176     // w1t row count (zero rows 2104..2175)
#define N2        1024
#define SHIST     50
#define NGRP      1024
#define NT1       33       // gemm1 K-tiles of 64
#define ITERS     16       // (NT1-1)/2
#define GMAX2     8        // max history-groups per 256-row tile (<=7 actual)

__device__ __forceinline__ ushort_t f2bf(float f) {
  union { float f; unsigned u; } v; v.f = f;
  unsigned r = v.u + 0x7FFF + ((v.u >> 16) & 1);
  return (ushort_t)(r >> 16);
}

__device__ __forceinline__ bf16x8 cvt8(f32x4 a0, f32x4 a1) {
  bf16x8 v;
  v[0] = (__bf16)a0[0]; v[1] = (__bf16)a0[1];
  v[2] = (__bf16)a0[2]; v[3] = (__bf16)a0[3];
  v[4] = (__bf16)a1[0]; v[5] = (__bf16)a1[1];
  v[6] = (__bf16)a1[2]; v[7] = (__bf16)a1[3];
  return v;
}

__device__ __forceinline__ void async_cp16(const void* g, void* l) {
  __builtin_amdgcn_global_load_lds(
      (const __attribute__((address_space(1))) void*)g,
      (__attribute__((address_space(3))) void*)l,
      16, 0, 0);
}

// ---------------- weight packs: LDS-tile transpose, coalesced both sides ----------------
// W1 f32 [2104][2104] (k,n) -> W1T bf16 [2176][2112] (n,k), zero padded
__global__ __launch_bounds__(256)
void pack_w1t(const float* __restrict__ w1, ushort_t* __restrict__ w1t) {
  __shared__ float t[64][65];
  const int kb = blockIdx.x * 64;           // k base, grid.x=33 -> k<2112
  const int nb = blockIdx.y * 64;           // n base, grid.y=34 -> n<2176
  const int tid = threadIdx.x;
  const int c = tid & 63, r4 = tid >> 6;
#pragma unroll
  for (int i = 0; i < 16; ++i) {
    int kl = i * 4 + r4;
    int k = kb + kl, n = nb + c;
    t[kl][c] = (k < K1 && n < K1) ? w1[(long)k * K1 + n] : 0.f;
  }
  __syncthreads();
#pragma unroll
  for (int i = 0; i < 16; ++i) {
    int nl = i * 4 + r4;
    w1t[(long)(nb + nl) * K1P + kb + c] = f2bf(t[c][nl]);
  }
}

// W2 f32 [2104][1024] -> W2T bf16 [1024][2112]
__global__ __launch_bounds__(256)
void pack_w2t(const float* __restrict__ w2, ushort_t* __restrict__ w2t) {
  __shared__ float t[64][65];
  const int kb = blockIdx.x * 64;           // grid.x=33 -> k<2112
  const int nb = blockIdx.y * 64;           // grid.y=16 -> n<1024
  const int tid = threadIdx.x;
  const int c = tid & 63, r4 = tid >> 6;
#pragma unroll
  for (int i = 0; i < 16; ++i) {
    int kl = i * 4 + r4;
    int k = kb + kl;
    t[kl][c] = (k < K1) ? w2[(long)k * N2 + nb + c] : 0.f;
  }
  __syncthreads();
#pragma unroll
  for (int i = 0; i < 16; ++i) {
    int nl = i * 4 + r4;
    w2t[(long)(nb + nl) * K1P + kb + c] = f2bf(t[c][nl]);
  }
}

// ---------------- mask compaction ----------------
__global__ void grp_count(const int* __restrict__ mask, int* __restrict__ cnt) {
  int g = blockIdx.x * 256 + threadIdx.x;
  if (g >= NGRP) return;
  const int* mp = mask + (long)g * SHIST;
  int c = 0;
#pragma unroll
  for (int s = 0; s < SHIST; ++s) c += (mp[s] != 0);
  cnt[g] = c;
}

__global__ void grp_scan(int* __restrict__ offs, float* __restrict__ cntf,
                         int* __restrict__ hdr) {
  __shared__ int sc[NGRP];
  const int t = threadIdx.x;
  const int c = offs[t];
  cntf[t] = (float)c;
  sc[t] = c;
  __syncthreads();
  for (int d = 1; d < NGRP; d <<= 1) {
    int add = (t >= d) ? sc[t - d] : 0;
    __syncthreads();
    sc[t] += add;
    __syncthreads();
  }
  offs[t] = sc[t] - c;
  if (t == NGRP - 1) {
    hdr[0] = sc[t];                          // total unmasked rows
    hdr[1] = (sc[t] + 255) & ~255;           // padded to 256 (BM)
  }
}

__global__ void pad_fill(const int* __restrict__ hdr, int* __restrict__ rowgrp) {
  int pos = blockIdx.x * 256 + threadIdx.x;
  if (pos < M_TOTAL && pos >= hdr[0]) rowgrp[pos] = -1;
}

__global__ void build_map(const int* __restrict__ mask, const int* __restrict__ offs,
                          int* __restrict__ rowmap, int* __restrict__ rowgrp) {
  const int g = blockIdx.x;
  const int lane = threadIdx.x;   // 64
  int ok = (lane < SHIST) ? (mask[(long)g * SHIST + lane] != 0) : 0;
  unsigned long long bal = __ballot(ok);
  if (ok) {
    int rank = __popcll(bal & ((1ull << lane) - 1ull));
    int pos = offs[g] + rank;
    rowmap[pos] = g * SHIST + lane;
    rowgrp[pos] = g;
  }
}

// gather+convert compacted rows into X bf16 [padded][2112]; one block per row
__global__ __launch_bounds__(256)
void pack_x(const float* __restrict__ emb, const float* __restrict__ vis,
            const float* __restrict__ bbox, const float* __restrict__ kp,
            const int* __restrict__ hdr, const int* __restrict__ rowmap,
            const int* __restrict__ rowgrp, ushort_t* __restrict__ X) {
  const int pos = blockIdx.x;
  if (pos >= hdr[1]) return;
  const int t = threadIdx.x;
  ushort_t* xr = X + (long)pos * K1P;
  const int g = rowgrp[pos];
  if (g < 0) {
    f32x4 z = {0.f, 0.f, 0.f, 0.f};
    for (int c = t; c < K1P / 8; c += 256) *(f32x4*)&xr[c * 8] = z;
    return;
  }
  const long r = rowmap[pos];
  {
    const float* src = emb + r * 2048 + t * 8;
    f32x4 a0 = *(const f32x4*)src;
    f32x4 a1 = *(const f32x4*)(src + 4);
    *(bf16x8*)&xr[t * 8] = cvt8(a0, a1);
  }
  if (t < 64) {
    float v = 0.f;
    if (t == 0)       v = vis[r];
    else if (t < 5)   v = bbox[r * 4 + (t - 1)];
    else if (t < 56)  v = kp[r * 51 + (t - 5)];
    xr[2048 + t] = f2bf(v);
  }
}

__global__ void zero_g(float* __restrict__ G) {
  G[blockIdx.x * 256 + threadIdx.x] = 0.f;
}

// ---------------- GEMM1: 256x256x64 8-phase, fused group-reduce ----------------
// G[g][n] += relu(X @ W1 + b1), summed over unmasked rows of each history group.

#define STAGE_A(S, H, KT) do {                                                  \
    int ci0 = tid, ci1 = 512 + tid;                                             \
    int r0_ = ci0 >> 3, r1_ = ci1 >> 3;                                         \
    async_cp16(&X[(long)(m0 + (H)*128 + r0_) * K1P + (KT)*64 +                  \
                  (((ci0 & 7) ^ (r0_ & 7)) << 3)],                              \
               &sA##S[(H)*8192 + ci0 * 8]);                                     \
    async_cp16(&X[(long)(m0 + (H)*128 + r1_) * K1P + (KT)*64 +                  \
                  (((ci1 & 7) ^ (r1_ & 7)) << 3)],                              \
               &sA##S[(H)*8192 + ci1 * 8]);                                     \
  } while (0)

#define STAGE_B(S, H, KT) do {                                                  \
    int ci0 = tid, ci1 = 512 + tid;                                             \
    int r0_ = ci0 >> 3, r1_ = ci1 >> 3;                                         \
    int gg0 = n0 + (H)*128 + r0_; if (gg0 >= N1P) gg0 = 2104 + (gg0 & 63);      \
    int gg1 = n0 + (H)*128 + r1_; if (gg1 >= N1P) gg1 = 2104 + (gg1 & 63);      \
    async_cp16(&w1t[(long)gg0 * K1P + (KT)*64 +                                 \
                    (((ci0 & 7) ^ (r0_ & 7)) << 3)],                            \
               &sB##S[(H)*8192 + ci0 * 8]);                                     \
    async_cp16(&w1t[(long)gg1 * K1P + (KT)*64 +                                 \
                    (((ci1 & 7) ^ (r1_ & 7)) << 3)],                            \
               &sB##S[(H)*8192 + ci1 * 8]);                                     \
  } while (0)

#define DS_A(S, Q) do {                                                         \
    int ra0 = wrbase + (2*(Q))*16 + l15;                                        \
    int ra1 = wrbase + (2*(Q)+1)*16 + l15;                                      \
    af[0][0] = *(const bf16x8*)&sA##S[(ra0 << 6) + (((quad    ) ^ (ra0 & 7)) << 3)]; \
    af[0][1] = *(const bf16x8*)&sA##S[(ra0 << 6) + (((quad + 4) ^ (ra0 & 7)) << 3)]; \
    af[1][0] = *(const bf16x8*)&sA##S[(ra1 << 6) + (((quad    ) ^ (ra1 & 7)) << 3)]; \
    af[1][1] = *(const bf16x8*)&sA##S[(ra1 << 6) + (((quad + 4) ^ (ra1 & 7)) << 3)]; \
  } while (0)

#define DS_B1(S, NJ) do {                                                       \
    int rb_ = wcbase + (NJ)*16 + l15;                                           \
    bfr[NJ][0] = *(const bf16x8*)&sB##S[(rb_ << 6) + (((quad    ) ^ (rb_ & 7)) << 3)]; \
    bfr[NJ][1] = *(const bf16x8*)&sB##S[(rb_ << 6) + (((quad + 4) ^ (rb_ & 7)) << 3)]; \
  } while (0)

#define DS_B(S) do { DS_B1(S,0); DS_B1(S,1); DS_B1(S,2); DS_B1(S,3); } while (0)

#define MFMAS(Q) do {                                                           \
    _Pragma("unroll")                                                           \
    for (int nj = 0; nj < 4; ++nj) {                                            \
      acc[2*(Q)][nj]   = __builtin_amdgcn_mfma_f32_16x16x32_bf16(af[0][0], bfr[nj][0], acc[2*(Q)][nj],   0,0,0); \
      acc[2*(Q)][nj]   = __builtin_amdgcn_mfma_f32_16x16x32_bf16(af[0][1], bfr[nj][1], acc[2*(Q)][nj],   0,0,0); \
      acc[2*(Q)+1][nj] = __builtin_amdgcn_mfma_f32_16x16x32_bf16(af[1][0], bfr[nj][0], acc[2*(Q)+1][nj], 0,0,0); \
      acc[2*(Q)+1][nj] = __builtin_amdgcn_mfma_f32_16x16x32_bf16(af[1][1], bfr[nj][1], acc[2*(Q)+1][nj], 0,0,0); \
    }                                                                           \
  } while (0)

#define VMC4 asm volatile("s_waitcnt vmcnt(4)" ::: "memory")
#define VMC0 asm volatile("s_waitcnt vmcnt(0)" ::: "memory")
#define NOP  ((void)0)

#define PH(SLOT, Q, STG, WTC) do {                                              \
    if ((Q) == 0) { DS_B(SLOT); }                                               \
    DS_A(SLOT, Q);                                                              \
    STG;                                                                        \
    WTC;                                                                        \
    __builtin_amdgcn_s_barrier();                                               \
    asm volatile("s_waitcnt lgkmcnt(0)" ::: "memory");                          \
    __builtin_amdgcn_s_setprio(1);                                              \
    MFMAS(Q);                                                                   \
    __builtin_amdgcn_s_setprio(0);                                              \
    __builtin_amdgcn_s_barrier();                                               \
  } while (0)

__global__ __launch_bounds__(512, 2)
void gemm1(const ushort_t* __restrict__ X, const ushort_t* __restrict__ w1t,
           const float* __restrict__ b1, const int* __restrict__ hdr,
           const int* __restrict__ rowgrp, float* __restrict__ G) {
  // XCD-aware bijective swizzle over the 9x200 grid (1800 % 8 == 0)
  int id = blockIdx.y * 9 + blockIdx.x;
  id = (id & 7) * 225 + (id >> 3);
  const int m0 = (id / 9) * 256;
  const int n0 = (id % 9) * 256;
  if (m0 >= hdr[1]) return;

  // 131 KB LDS total; epilogue scratch overlays sA0/sB0 (dead after K-loop)
  __shared__ __align__(16) ushort_t sA0[16384], sA1[16384];
  __shared__ __align__(16) ushort_t sB0[16384], sB1[16384];

  const int tid  = threadIdx.x;
  const int lane = tid & 63;
  const int l15  = lane & 15;
  const int quad = lane >> 4;
  const int wave = tid >> 6;
  const int wrbase = (wave >> 2) * 128;     // 2 wave-rows
  const int wcbase = (wave & 3) * 64;       // 4 wave-cols

  f32x4 acc[8][4];
#pragma unroll
  for (int i = 0; i < 8; ++i)
#pragma unroll
    for (int j = 0; j < 4; ++j) {
      f32x4 z = {0.f, 0.f, 0.f, 0.f};
      acc[i][j] = z;
    }

  bf16x8 af[2][2], bfr[4][2];

  // prologue: slot0 full (tile 0), slot1.B (tile 1); slot1.A staged in P1/P2
  STAGE_A(0, 0, 0); STAGE_A(0, 1, 0);
  STAGE_B(0, 0, 0); STAGE_B(0, 1, 0);
  STAGE_B(1, 0, 1); STAGE_B(1, 1, 1);
  VMC4;
  __builtin_amdgcn_s_barrier();

  for (int it = 0; it < ITERS; ++it) {
    const int t1 = 2 * it + 1, t2 = 2 * it + 2, t3 = 2 * it + 3;
    // phases 1-4: compute slot0 (tile 2it)
    PH(0, 0, STAGE_A(1, 0, t1), NOP);
    PH(0, 1, STAGE_A(1, 1, t1), NOP);
    PH(0, 2, STAGE_B(0, 0, t2), NOP);
    PH(0, 3, STAGE_B(0, 1, t2), VMC4);
    // phases 5-8: compute slot1 (tile 2it+1)
    PH(1, 0, STAGE_A(0, 0, t2), NOP);
    PH(1, 1, STAGE_A(0, 1, t2), NOP);
    PH(1, 2, if (t3 < NT1) STAGE_B(1, 0, t3), NOP);
    PH(1, 3, if (t3 < NT1) { STAGE_B(1, 1, t3); VMC4; } else { VMC0; }, NOP);
  }
  // tail: tile 32 in slot0 (fully staged; drained by VMC0 above)
  PH(0, 0, NOP, NOP);
  PH(0, 1, NOP, NOP);
  PH(0, 2, NOP, NOP);
  PH(0, 3, NOP, NOP);

  // ---- epilogue: bias + relu, per-group reduce (LDS scratch overlays sA0/sB0) ----
  __syncthreads();
  float* sgrp = (float*)sA0;                // GMAX2*256 floats = 8 KB
  int*   srg  = (int*)sB0;                  // 256 ints
  if (tid < 256) srg[tid] = rowgrp[m0 + tid];
  for (int z = tid; z < GMAX2 * 256; z += 512) sgrp[z] = 0.f;
  __syncthreads();

  const int gf = srg[0];                    // min group in tile (>=0 for live tiles)
#pragma unroll
  for (int mi = 0; mi < 8; ++mi) {
    const int lr0 = wrbase + mi * 16 + quad * 4;
#pragma unroll
    for (int nj = 0; nj < 4; ++nj) {
      const int cl = wcbase + nj * 16 + l15;
      const int n  = n0 + cl;
      if (n < K1P) {
        const float bv = (n < K1) ? b1[n] : 0.f;
        float s = 0.f;
        int gp = srg[lr0];
#pragma unroll
        for (int r = 0; r < 4; ++r) {
          int g = srg[lr0 + r];
          if (g != gp) {
            if (gp >= 0 && s != 0.f) {
              int gi = gp - gf;
              if (gi < GMAX2) atomicAdd(&sgrp[gi * 256 + cl], s);
              else            atomicAdd(&G[(long)gp * K1P + n], s);
            }
            s = 0.f; gp = g;
          }
          if (g >= 0) s += fmaxf(acc[mi][nj][r] + bv, 0.f);
        }
        if (gp >= 0 && s != 0.f) {
          int gi = gp - gf;
          if (gi < GMAX2) atomicAdd(&sgrp[gi * 256 + cl], s);
          else            atomicAdd(&G[(long)gp * K1P + n], s);
        }
      }
    }
  }
  __syncthreads();
  for (int z = tid; z < GMAX2 * 256; z += 512) {
    float v = sgrp[z];
    if (v != 0.f) {
      int gi = z >> 8, cl = z & 255;
      int n = n0 + cl;
      int g = gf + gi;
      if (n < K1P && g < NGRP) atomicAdd(&G[(long)g * K1P + n], v);
    }
  }
}

// ---------------- GEMM2 (tiny, 64x64 tiles -> 256 blocks): out = (G @ W2 + cnt*b2)/50 ----
__global__ __launch_bounds__(256)
void gemm2(const float* __restrict__ G, const ushort_t* __restrict__ w2t,
           const float* __restrict__ b2, const float* __restrict__ cntf,
           float* __restrict__ out) {
  __shared__ __align__(16) ushort_t lah[64 * 32], lal[64 * 32], lb[64 * 32];
  const int tid  = threadIdx.x;
  const int lane = tid & 63;
  const int l15  = lane & 15;
  const int quad = lane >> 4;
  const int wave = tid >> 6;
  const int wm   = (wave & 1) * 32;
  const int wn   = (wave >> 1) * 32;
  int id = blockIdx.y * 16 + blockIdx.x;
  id = (id & 7) * 32 + (id >> 3);           // XCD swizzle (256 % 8 == 0)
  const int m0 = (id >> 4) * 64;
  const int n0 = (id & 15) * 64;

  f32x4 acc[2][2];
#pragma unroll
  for (int i = 0; i < 2; ++i)
#pragma unroll
    for (int j = 0; j < 2; ++j) {
      f32x4 z = {0.f, 0.f, 0.f, 0.f};
      acc[i][j] = z;
    }

  const int row = tid >> 2, kc = (tid & 3) * 8;
  for (int ks = 0; ks < K1P / 32; ++ks) {   // 66
    const int k0 = ks * 32;
    async_cp16(&w2t[(long)(n0 + row) * K1P + k0 + kc], &lb[tid * 8]);
    const float* src = &G[(long)(m0 + row) * K1P + k0 + kc];
    f32x4 a0 = *(const f32x4*)src;
    f32x4 a1 = *(const f32x4*)(src + 4);
    bf16x8 hi = cvt8(a0, a1);
    f32x4 r0v, r1v;
#pragma unroll
    for (int e = 0; e < 4; ++e) {
      r0v[e] = a0[e] - (float)hi[e];
      r1v[e] = a1[e] - (float)hi[e + 4];
    }
    bf16x8 lo = cvt8(r0v, r1v);
    *(bf16x8*)&lah[tid * 8] = hi;
    *(bf16x8*)&lal[tid * 8] = lo;
    __syncthreads();
    bf16x8 ah[2], al[2], bf_[2];
#pragma unroll
    for (int mi = 0; mi < 2; ++mi) {
      int ra = wm + mi * 16 + l15;
      ah[mi] = *(const bf16x8*)&lah[ra * 32 + quad * 8];
      al[mi] = *(const bf16x8*)&lal[ra * 32 + quad * 8];
    }
#pragma unroll
    for (int nj = 0; nj < 2; ++nj) {
      int rb = wn + nj * 16 + l15;
      bf_[nj] = *(const bf16x8*)&lb[rb * 32 + quad * 8];
    }
#pragma unroll
    for (int mi = 0; mi < 2; ++mi)
#pragma unroll
      for (int nj = 0; nj < 2; ++nj) {
        acc[mi][nj] = __builtin_amdgcn_mfma_f32_16x16x32_bf16(ah[mi], bf_[nj], acc[mi][nj], 0, 0, 0);
        acc[mi][nj] = __builtin_amdgcn_mfma_f32_16x16x32_bf16(al[mi], bf_[nj], acc[mi][nj], 0, 0, 0);
      }
    __syncthreads();
  }

#pragma unroll
  for (int mi = 0; mi < 2; ++mi) {
    int gb = m0 + wm + mi * 16 + quad * 4;
#pragma unroll
    for (int nj = 0; nj < 2; ++nj) {
      int n = n0 + wn + nj * 16 + l15;
      float bv = b2[n];
#pragma unroll
      for (int r = 0; r < 4; ++r) {
        int g = gb + r;
        out[(long)g * N2 + n] = (acc[mi][nj][r] + cntf[g] * bv) * (1.0f / 50.0f);
      }
    }
  }
}

extern "C" void kernel_launch(void* const* d_in, const int* in_sizes, int n_in,
                              void* d_out, int out_size, void* d_ws, size_t ws_size,
                              hipStream_t stream) {
  const float* emb  = (const float*)d_in[0];
  const float* vis  = (const float*)d_in[1];
  const float* bbox = (const float*)d_in[2];
  const float* kp   = (const float*)d_in[3];
  const int*   mask = (const int*)d_in[4];
  const float* w1   = (const float*)d_in[5];
  const float* b1   = (const float*)d_in[6];
  const float* w2   = (const float*)d_in[7];
  const float* b2   = (const float*)d_in[8];
  float* out = (float*)d_out;

  // ws layout (bytes), all 16B aligned; total = 238,854,160 (same as verified round 1)
  char* ws = (char*)d_ws;
  ushort_t* w1t    = (ushort_t*)(ws);               //  9,191,424 (2176*2112*2)
  ushort_t* w2t    = (ushort_t*)(ws +  9191424);    //  4,325,376 (1024*2112*2)
  float*    G      = (float*)   (ws + 13516800);    //  8,650,752 (1024*2112*4)
  float*    cntf   = (float*)   (ws + 22167552);    //      4,096
  int*      offs   = (int*)     (ws + 22171648);    //      4,096
  int*      hdr    = (int*)     (ws + 22175744);    //         16
  int*      rowmap = (int*)     (ws + 22175760);    //    204,800
  int*      rowgrp = (int*)     (ws + 22380560);    //    204,800
  ushort_t* X      = (ushort_t*)(ws + 22585360);    // 216,268,800 (51200*2112*2)

  pack_w1t<<<dim3(33, 34), 256, 0, stream>>>(w1, w1t);
  pack_w2t<<<dim3(33, 16), 256, 0, stream>>>(w2, w2t);

  grp_count<<<dim3(NGRP / 256), 256, 0, stream>>>(mask, offs);
  grp_scan<<<dim3(1), NGRP, 0, stream>>>(offs, cntf, hdr);
  pad_fill<<<dim3(M_TOTAL / 256), 256, 0, stream>>>(hdr, rowgrp);
  build_map<<<dim3(NGRP), 64, 0, stream>>>(mask, offs, rowmap, rowgrp);
  pack_x<<<dim3(M_TOTAL), 256, 0, stream>>>(emb, vis, bbox, kp, hdr, rowmap, rowgrp, X);
  zero_g<<<dim3(NGRP * K1P / 256), 256, 0, stream>>>(G);

  gemm1<<<dim3(9, 200), 512, 0, stream>>>(X, w1t, b1, hdr, rowgrp, G);
  gemm2<<<dim3(16, 16), 256, 0, stream>>>(G, w2t, b2, cntf, out);
}